// Round 1
// baseline (10236.172 us; speedup 1.0000x reference)
//
#include <hip/hip_runtime.h>
#include <hip/hip_cooperative_groups.h>
#include <math.h>

namespace cg = cooperative_groups;

// ---------------- retrieve_key: [256] queries vs [15] keys over L=150528 ----
#define L_TOT  150528
#define ROW4   37632      // L_TOT/4 float4 per row
#define NCHUNK 7
#define CH4    5376       // ROW4/NCHUNK
#define R_ITERS 84        // CH4/64
#define NBT    32         // b-tiles of 8
#define BTILE  8
#define NCLS   15

// ---------------- FPS ------------------------------------------------------
#define N_E    12544
#define DIM    768
#define NBLK   256
#define PPB    49         // points per block (256*49 = 12544)
#define NPW    13         // max points per wave (4 waves: 13,13,13,10)
#define NSAMP  196

__device__ __forceinline__ float wave_sum(float v) {
#pragma unroll
  for (int m = 1; m < 64; m <<= 1) v += __shfl_xor(v, m, 64);
  return v;
}

// Partial dot products: grid (32 b-tiles, 7 L-chunks), block 256.
// Wave w handles classes [4w, 4w+cnt); wave 3 also accumulates |q|^2,
// bt==0 blocks also accumulate |k|^2 partials.
__global__ __launch_bounds__(256) void retrieve_partial(
    const float* __restrict__ q, const float* __restrict__ k,
    float* __restrict__ part, float* __restrict__ kkpart) {
  const int bt = blockIdx.x;     // 0..31
  const int lc = blockIdx.y;     // 0..6
  const int tid = threadIdx.x;
  const int w = tid >> 6, lane = tid & 63;
  const int cbase = w * 4;
  const int ccnt = (w == 3) ? 3 : 4;
  const float4* qf = (const float4*)q;
  const float4* kf = (const float4*)k;
  const int fbase = lc * CH4 + lane;

  float acc[BTILE][4];
  float qq[BTILE];
  float kkv[4];
#pragma unroll
  for (int b = 0; b < BTILE; ++b) {
    qq[b] = 0.f;
#pragma unroll
    for (int c = 0; c < 4; ++c) acc[b][c] = 0.f;
  }
#pragma unroll
  for (int c = 0; c < 4; ++c) kkv[c] = 0.f;

  for (int it = 0; it < R_ITERS; ++it) {
    const int f = fbase + it * 64;
    float4 kv[4];
#pragma unroll
    for (int c = 0; c < 4; ++c)
      if (c < ccnt) kv[c] = kf[(size_t)(cbase + c) * ROW4 + f];
    if (bt == 0) {
#pragma unroll
      for (int c = 0; c < 4; ++c)
        if (c < ccnt)
          kkv[c] += kv[c].x*kv[c].x + kv[c].y*kv[c].y + kv[c].z*kv[c].z + kv[c].w*kv[c].w;
    }
#pragma unroll
    for (int b = 0; b < BTILE; ++b) {
      float4 qv = qf[(size_t)(bt * BTILE + b) * ROW4 + f];
#pragma unroll
      for (int c = 0; c < 4; ++c)
        if (c < ccnt)
          acc[b][c] += qv.x*kv[c].x + qv.y*kv[c].y + qv.z*kv[c].z + qv.w*kv[c].w;
      if (w == 3)
        qq[b] += qv.x*qv.x + qv.y*qv.y + qv.z*qv.z + qv.w*qv.w;
    }
  }

  const size_t pb = (size_t)(lc * NBT + bt) * 16;
#pragma unroll
  for (int b = 0; b < BTILE; ++b) {
#pragma unroll
    for (int c = 0; c < 4; ++c) {
      float v = wave_sum(acc[b][c]);
      if (lane == 0 && c < ccnt) part[(pb + cbase + c) * 8 + b] = v;
    }
    if (w == 3) {
      float v = wave_sum(qq[b]);
      if (lane == 0) part[(pb + 15) * 8 + b] = v;
    }
  }
  if (bt == 0) {
#pragma unroll
    for (int c = 0; c < 4; ++c) {
      float v = wave_sum(kkv[c]);
      if (lane == 0 && c < ccnt) kkpart[lc * 16 + cbase + c] = v;
    }
  }
}

// Final reduce: 1 block, thread b handles query b.
__global__ __launch_bounds__(256) void retrieve_reduce(
    const float* __restrict__ part, const float* __restrict__ kkpart,
    float* __restrict__ out) {
  __shared__ float kn[NCLS];
  const int t = threadIdx.x;
  if (t < NCLS) {
    float s = 0.f;
    for (int lc = 0; lc < NCHUNK; ++lc) s += kkpart[lc * 16 + t];
    kn[t] = s;
  }
  __syncthreads();
  const int bt = t >> 3, bi = t & 7;
  float qq = 0.f;
  for (int lc = 0; lc < NCHUNK; ++lc)
    qq += part[((size_t)(lc * NBT + bt) * 16 + 15) * 8 + bi];
  float dmin = INFINITY;
  int didx = 0;
  for (int c = 0; c < NCLS; ++c) {
    float dot = 0.f;
    for (int lc = 0; lc < NCHUNK; ++lc)
      dot += part[((size_t)(lc * NBT + bt) * 16 + c) * 8 + bi];
    float d2 = qq + kn[c] - 2.f * dot;
    float d = sqrtf(fmaxf(d2, 1e-12f));
    if (d < dmin) { dmin = d; didx = c; }
  }
  out[t] = dmin;
  out[256 + t] = (float)didx;
}

// Persistent cooperative FPS kernel. 256 blocks x 256 threads, 1 block/CU.
// Each wave owns <=13 points; embedding rows preloaded into registers.
__global__ __launch_bounds__(256, 1) void fps_kernel(
    const float* __restrict__ emb,
    unsigned long long* __restrict__ pkeys,   // [NBLK] per-block best key
    float* __restrict__ out_samples) {
  cg::grid_group grid = cg::this_grid();
  const int tid = threadIdx.x;
  const int blk = blockIdx.x;
  const int w = tid >> 6, lane = tid & 63;

  __shared__ int hist[NSAMP];
  __shared__ unsigned long long wkey[4];
  __shared__ unsigned long long sh[NBLK];

  // Preload this wave's points into registers; compute squared norms.
  float e[NPW][12];
  float sq[NPW];
  float dist2[NPW];
  const int pbase = blk * PPB + w * NPW;
#pragma unroll
  for (int i = 0; i < NPW; ++i) {
    const bool valid = (w * NPW + i) < PPB;
    const size_t g = (size_t)(pbase + i) * DIM;
    float s = 0.f;
#pragma unroll
    for (int j = 0; j < 12; ++j) {
      float v = valid ? emb[g + lane + 64 * j] : 0.f;
      e[i][j] = v;
      s += v * v;
    }
    sq[i] = wave_sum(s);
    dist2[i] = INFINITY;
  }
  int last = 0;
  if (tid == 0) hist[0] = 0;

  for (int s = 1; s < NSAMP; ++s) {
    // Load centroid row (uniform across grid), compute |c|^2.
    float c[12];
    float cn = 0.f;
    const size_t cb = (size_t)last * DIM;
#pragma unroll
    for (int j = 0; j < 12; ++j) {
      float v = emb[cb + lane + 64 * j];
      c[j] = v;
      cn += v * v;
    }
    cn = wave_sum(cn);

    // Update running min (squared space) and track wave-local argmax.
    unsigned long long bk = 0ull;
#pragma unroll
    for (int i = 0; i < NPW; ++i) {
      if (w * NPW + i < PPB) {
        float a = 0.f;
#pragma unroll
        for (int j = 0; j < 12; ++j) a = fmaf(e[i][j], c[j], a);
        a = wave_sum(a);
        float d2 = sq[i] - 2.f * a + cn;
        if (d2 < dist2[i]) dist2[i] = d2;
        unsigned fb = __float_as_uint(dist2[i]);
        unsigned long long key =
            ((unsigned long long)fb << 32) | (unsigned)(~(unsigned)(pbase + i));
        if (key > bk) bk = key;
      }
    }
    if (lane == 0) wkey[w] = bk;
    __syncthreads();
    if (tid == 0) {
      unsigned long long m = wkey[0];
#pragma unroll
      for (int qi = 1; qi < 4; ++qi) if (wkey[qi] > m) m = wkey[qi];
      pkeys[blk] = m;
    }
    __threadfence();   // release: make our slot visible device-wide
    grid.sync();

    // Every block redundantly reduces all 256 partials -> same `last`.
    sh[tid] = pkeys[tid];
    __syncthreads();
    for (int off = NBLK / 2; off > 0; off >>= 1) {
      if (tid < off) {
        if (sh[tid + off] > sh[tid]) sh[tid] = sh[tid + off];
      }
      __syncthreads();
    }
    const int nxt = (int)(~(unsigned)(sh[0] & 0xffffffffu));
    if (tid == 0) hist[s] = nxt;
    __syncthreads();
    last = nxt;
  }

  // Gather samples: block blk copies row hist[blk] (no cross-block dep).
  if (blk < NSAMP) {
    const int idx = hist[blk];
    const float4* src = (const float4*)(emb + (size_t)idx * DIM);
    float4* dst = (float4*)(out_samples + (size_t)blk * DIM);
    if (tid < DIM / 4) dst[tid] = src[tid];
  }
}

extern "C" void kernel_launch(void* const* d_in, const int* in_sizes, int n_in,
                              void* d_out, int out_size, void* d_ws, size_t ws_size,
                              hipStream_t stream) {
  const float* q   = (const float*)d_in[0];   // [256, 196, 768]
  const float* k   = (const float*)d_in[1];   // [15, 196, 768]
  const float* emb = (const float*)d_in[2];   // [12544, 768]
  float* out = (float*)d_out;                 // [256 dist | 256 idx | 196*768 samples]

  unsigned long long* pkeys = (unsigned long long*)d_ws;        // 256 u64 = 2048 B
  float* part   = (float*)((char*)d_ws + 2048);                 // 7*32*16*8 = 28672 f
  float* kkpart = part + 28672;                                 // 112 f

  hipLaunchKernelGGL(retrieve_partial, dim3(NBT, NCHUNK), dim3(256), 0, stream,
                     q, k, part, kkpart);
  hipLaunchKernelGGL(retrieve_reduce, dim3(1), dim3(256), 0, stream,
                     part, kkpart, out);

  float* samples = out + 512;
  void* args[] = {(void*)&emb, (void*)&pkeys, (void*)&samples};
  hipLaunchCooperativeKernel((void*)fps_kernel, dim3(NBLK), dim3(256), args, 0,
                             stream);
}

// Round 2
// 5511.414 us; speedup vs baseline: 1.8573x; 1.8573x over previous
//
#include <hip/hip_runtime.h>
#include <hip/hip_cooperative_groups.h>
#include <math.h>

// ---------------- retrieve_key: [256] queries vs [15] keys over L=150528 ----
#define L_TOT  150528
#define ROW4   37632      // L_TOT/4 float4 per row
#define NCHUNK 7
#define CH4    5376       // ROW4/NCHUNK
#define R_ITERS 84        // CH4/64
#define NBT    32         // b-tiles of 8
#define BTILE  8
#define NCLS   15

// ---------------- FPS ------------------------------------------------------
#define N_E    12544
#define DIM    768
#define NBLK   256
#define PPB    49         // points per block (256*49 = 12544)
#define NPPW   4          // max points per wave (16 waves: wave0 gets 4)
#define NSAMP  196

__device__ __forceinline__ float wave_sum(float v) {
#pragma unroll
  for (int m = 1; m < 64; m <<= 1) v += __shfl_xor(v, m, 64);
  return v;
}

__device__ __forceinline__ unsigned long long wave_max_u64(unsigned long long v) {
#pragma unroll
  for (int m = 1; m < 64; m <<= 1) {
    unsigned long long o = __shfl_xor(v, m, 64);
    if (o > v) v = o;
  }
  return v;
}

// Partial dot products: grid (32 b-tiles, 7 L-chunks), block 256.
__global__ __launch_bounds__(256) void retrieve_partial(
    const float* __restrict__ q, const float* __restrict__ k,
    float* __restrict__ part, float* __restrict__ kkpart) {
  const int bt = blockIdx.x;     // 0..31
  const int lc = blockIdx.y;     // 0..6
  const int tid = threadIdx.x;
  const int w = tid >> 6, lane = tid & 63;
  const int cbase = w * 4;
  const int ccnt = (w == 3) ? 3 : 4;
  const float4* qf = (const float4*)q;
  const float4* kf = (const float4*)k;
  const int fbase = lc * CH4 + lane;

  float acc[BTILE][4];
  float qq[BTILE];
  float kkv[4];
#pragma unroll
  for (int b = 0; b < BTILE; ++b) {
    qq[b] = 0.f;
#pragma unroll
    for (int c = 0; c < 4; ++c) acc[b][c] = 0.f;
  }
#pragma unroll
  for (int c = 0; c < 4; ++c) kkv[c] = 0.f;

  for (int it = 0; it < R_ITERS; ++it) {
    const int f = fbase + it * 64;
    float4 kv[4];
#pragma unroll
    for (int c = 0; c < 4; ++c)
      if (c < ccnt) kv[c] = kf[(size_t)(cbase + c) * ROW4 + f];
    if (bt == 0) {
#pragma unroll
      for (int c = 0; c < 4; ++c)
        if (c < ccnt)
          kkv[c] += kv[c].x*kv[c].x + kv[c].y*kv[c].y + kv[c].z*kv[c].z + kv[c].w*kv[c].w;
    }
#pragma unroll
    for (int b = 0; b < BTILE; ++b) {
      float4 qv = qf[(size_t)(bt * BTILE + b) * ROW4 + f];
#pragma unroll
      for (int c = 0; c < 4; ++c)
        if (c < ccnt)
          acc[b][c] += qv.x*kv[c].x + qv.y*kv[c].y + qv.z*kv[c].z + qv.w*kv[c].w;
      if (w == 3)
        qq[b] += qv.x*qv.x + qv.y*qv.y + qv.z*qv.z + qv.w*qv.w;
    }
  }

  const size_t pb = (size_t)(lc * NBT + bt) * 16;
#pragma unroll
  for (int b = 0; b < BTILE; ++b) {
#pragma unroll
    for (int c = 0; c < 4; ++c) {
      float v = wave_sum(acc[b][c]);
      if (lane == 0 && c < ccnt) part[(pb + cbase + c) * 8 + b] = v;
    }
    if (w == 3) {
      float v = wave_sum(qq[b]);
      if (lane == 0) part[(pb + 15) * 8 + b] = v;
    }
  }
  if (bt == 0) {
#pragma unroll
    for (int c = 0; c < 4; ++c) {
      float v = wave_sum(kkv[c]);
      if (lane == 0 && c < ccnt) kkpart[lc * 16 + cbase + c] = v;
    }
  }
}

// Final reduce: 1 block, thread b handles query b.
__global__ __launch_bounds__(256) void retrieve_reduce(
    const float* __restrict__ part, const float* __restrict__ kkpart,
    float* __restrict__ out) {
  __shared__ float kn[NCLS];
  const int t = threadIdx.x;
  if (t < NCLS) {
    float s = 0.f;
    for (int lc = 0; lc < NCHUNK; ++lc) s += kkpart[lc * 16 + t];
    kn[t] = s;
  }
  __syncthreads();
  const int bt = t >> 3, bi = t & 7;
  float qq = 0.f;
  for (int lc = 0; lc < NCHUNK; ++lc)
    qq += part[((size_t)(lc * NBT + bt) * 16 + 15) * 8 + bi];
  float dmin = INFINITY;
  int didx = 0;
  for (int c = 0; c < NCLS; ++c) {
    float dot = 0.f;
    for (int lc = 0; lc < NCHUNK; ++lc)
      dot += part[((size_t)(lc * NBT + bt) * 16 + c) * 8 + bi];
    float d2 = qq + kn[c] - 2.f * dot;
    float d = sqrtf(fmaxf(d2, 1e-12f));
    if (d < dmin) { dmin = d; didx = c; }
  }
  out[t] = dmin;
  out[256 + t] = (float)didx;
}

// Persistent cooperative FPS kernel. 256 blocks x 1024 threads (16 waves/CU).
// Wave w owns points {w + 16*i}; embedding rows live in registers (no spill).
// Cross-block barrier: per-block tag write + per-thread read-only spin
// (no serialized RMW atomics, unlike cg::grid_group::sync).
__global__ __launch_bounds__(1024, 4) void fps_kernel(
    const float* __restrict__ emb,
    unsigned long long* __restrict__ pkeys,   // [NBLK] per-block best key
    int* __restrict__ arr,                    // [NBLK] per-block step tag (memset 0)
    float* __restrict__ out_samples) {
  const int tid = threadIdx.x;
  const int blk = blockIdx.x;
  const int w = tid >> 6, lane = tid & 63;

  __shared__ int hist[NSAMP];
  __shared__ unsigned long long wkey[16];
  __shared__ unsigned long long swin[4];

  // Preload this wave's points into registers; compute squared norms.
  float e[NPPW][12];
  float sq[NPPW];
  float dist2[NPPW];
#pragma unroll
  for (int i = 0; i < NPPW; ++i) {
    const int p = w + 16 * i;
    const bool valid = p < PPB;
    const size_t g = (size_t)(blk * PPB + p) * DIM;
    float s = 0.f;
#pragma unroll
    for (int j = 0; j < 12; ++j) {
      float v = valid ? emb[g + lane + 64 * j] : 0.f;
      e[i][j] = v;
      s += v * v;
    }
    sq[i] = wave_sum(s);
    dist2[i] = INFINITY;
  }
  int last = 0;
  if (tid == 0) hist[0] = 0;

  for (int s = 1; s < NSAMP; ++s) {
    // Load centroid row (uniform), compute |c|^2 — same arithmetic as before.
    float c[12];
    float cn = 0.f;
    const size_t cb = (size_t)last * DIM;
#pragma unroll
    for (int j = 0; j < 12; ++j) {
      float v = emb[cb + lane + 64 * j];
      c[j] = v;
      cn += v * v;
    }
    cn = wave_sum(cn);

    // Update running min (squared space); wave-local best key.
    unsigned long long bk = 0ull;
#pragma unroll
    for (int i = 0; i < NPPW; ++i) {
      const int p = w + 16 * i;
      if (p < PPB) {
        float a = 0.f;
#pragma unroll
        for (int j = 0; j < 12; ++j) a = fmaf(e[i][j], c[j], a);
        a = wave_sum(a);
        float d2 = sq[i] - 2.f * a + cn;
        if (d2 < dist2[i]) dist2[i] = d2;
        unsigned fb = __float_as_uint(dist2[i]);
        unsigned long long key =
            ((unsigned long long)fb << 32) |
            (unsigned)(~(unsigned)(blk * PPB + p));
        if (key > bk) bk = key;
      }
    }
    if (lane == 0) wkey[w] = bk;
    __syncthreads();
    if (tid == 0) {
      unsigned long long m = wkey[0];
#pragma unroll
      for (int qi = 1; qi < 16; ++qi) if (wkey[qi] > m) m = wkey[qi];
      __hip_atomic_store(&pkeys[blk], m, __ATOMIC_RELAXED, __HIP_MEMORY_SCOPE_AGENT);
      __hip_atomic_store(&arr[blk], s, __ATOMIC_RELEASE, __HIP_MEMORY_SCOPE_AGENT);
    }

    // Tag barrier + global argmax: thread t<256 waits for block t's tag,
    // then reads its key; wave/LDS reduce; everyone learns the winner.
    if (tid < NBLK) {
      while (__hip_atomic_load(&arr[tid], __ATOMIC_ACQUIRE,
                               __HIP_MEMORY_SCOPE_AGENT) != s)
        __builtin_amdgcn_s_sleep(1);
      unsigned long long k = __hip_atomic_load(&pkeys[tid], __ATOMIC_RELAXED,
                                               __HIP_MEMORY_SCOPE_AGENT);
      k = wave_max_u64(k);
      if (lane == 0) swin[w] = k;
    }
    __syncthreads();
    if (tid == 0) {
      unsigned long long m = swin[0];
#pragma unroll
      for (int qi = 1; qi < 4; ++qi) if (swin[qi] > m) m = swin[qi];
      hist[s] = (int)(~(unsigned)(m & 0xffffffffu));
    }
    __syncthreads();
    last = hist[s];
  }

  // Gather samples: block blk copies row hist[blk] (no cross-block dep).
  if (blk < NSAMP) {
    const int idx = hist[blk];
    const float4* src = (const float4*)(emb + (size_t)idx * DIM);
    float4* dst = (float4*)(out_samples + (size_t)blk * DIM);
    if (tid < DIM / 4) dst[tid] = src[tid];
  }
}

extern "C" void kernel_launch(void* const* d_in, const int* in_sizes, int n_in,
                              void* d_out, int out_size, void* d_ws, size_t ws_size,
                              hipStream_t stream) {
  const float* q   = (const float*)d_in[0];   // [256, 196, 768]
  const float* k   = (const float*)d_in[1];   // [15, 196, 768]
  const float* emb = (const float*)d_in[2];   // [12544, 768]
  float* out = (float*)d_out;                 // [256 dist | 256 idx | 196*768 samples]

  unsigned long long* pkeys = (unsigned long long*)d_ws;        // 256 u64 = 2048 B
  int* arr = (int*)((char*)d_ws + 2048);                        // 256 int = 1024 B
  float* part   = (float*)((char*)d_ws + 3072);                 // 7*32*16*8 = 28672 f
  float* kkpart = part + 28672;                                 // 112 f

  // Reset step tags (stale tags from prior replays must not alias).
  hipMemsetAsync(arr, 0, NBLK * sizeof(int), stream);

  hipLaunchKernelGGL(retrieve_partial, dim3(NBT, NCHUNK), dim3(256), 0, stream,
                     q, k, part, kkpart);
  hipLaunchKernelGGL(retrieve_reduce, dim3(1), dim3(256), 0, stream,
                     part, kkpart, out);

  float* samples = out + 512;
  void* args[] = {(void*)&emb, (void*)&pkeys, (void*)&arr, (void*)&samples};
  hipLaunchCooperativeKernel((void*)fps_kernel, dim3(NBLK), dim3(1024), args, 0,
                             stream);
}

// Round 3
// 1142.529 us; speedup vs baseline: 8.9592x; 4.8239x over previous
//
#include <hip/hip_runtime.h>
#include <math.h>

typedef unsigned long long u64;
typedef unsigned int u32;

// ---------------- retrieve_key: [256] queries vs [15] keys over L=150528 ----
#define L_TOT  150528
#define ROW4   37632      // L_TOT/4 float4 per row
#define NCHUNK 7
#define CH4    5376       // ROW4/NCHUNK
#define R_ITERS 84        // CH4/64
#define NBT    32         // b-tiles of 8
#define BTILE  8
#define NCLS   15

// ---------------- FPS ------------------------------------------------------
#define N_E    12544
#define DIM    768
#define NBLK   256
#define PPB    49         // points per block (256*49 = 12544, exact)
#define NPPW   4          // max points per wave (wave 0 gets 4, others 3)
#define NSAMP  196
#define EPB    (PPB*DIM)  // 37632 floats = 150528 B in LDS

__device__ __forceinline__ float wave_sum(float v) {
#pragma unroll
  for (int m = 1; m < 64; m <<= 1) v += __shfl_xor(v, m, 64);
  return v;
}

__device__ __forceinline__ u64 wave_max_u64(u64 v) {
#pragma unroll
  for (int m = 1; m < 64; m <<= 1) {
    u64 o = __shfl_xor(v, m, 64);
    if (o > v) v = o;
  }
  return v;
}

// Partial dot products: grid (32 b-tiles, 7 L-chunks), block 256.
__global__ __launch_bounds__(256) void retrieve_partial(
    const float* __restrict__ q, const float* __restrict__ k,
    float* __restrict__ part, float* __restrict__ kkpart) {
  const int bt = blockIdx.x;     // 0..31
  const int lc = blockIdx.y;     // 0..6
  const int tid = threadIdx.x;
  const int w = tid >> 6, lane = tid & 63;
  const int cbase = w * 4;
  const int ccnt = (w == 3) ? 3 : 4;
  const float4* qf = (const float4*)q;
  const float4* kf = (const float4*)k;
  const int fbase = lc * CH4 + lane;

  float acc[BTILE][4];
  float qq[BTILE];
  float kkv[4];
#pragma unroll
  for (int b = 0; b < BTILE; ++b) {
    qq[b] = 0.f;
#pragma unroll
    for (int c = 0; c < 4; ++c) acc[b][c] = 0.f;
  }
#pragma unroll
  for (int c = 0; c < 4; ++c) kkv[c] = 0.f;

  for (int it = 0; it < R_ITERS; ++it) {
    const int f = fbase + it * 64;
    float4 kv[4];
#pragma unroll
    for (int c = 0; c < 4; ++c)
      if (c < ccnt) kv[c] = kf[(size_t)(cbase + c) * ROW4 + f];
    if (bt == 0) {
#pragma unroll
      for (int c = 0; c < 4; ++c)
        if (c < ccnt)
          kkv[c] += kv[c].x*kv[c].x + kv[c].y*kv[c].y + kv[c].z*kv[c].z + kv[c].w*kv[c].w;
    }
#pragma unroll
    for (int b = 0; b < BTILE; ++b) {
      float4 qv = qf[(size_t)(bt * BTILE + b) * ROW4 + f];
#pragma unroll
      for (int c = 0; c < 4; ++c)
        if (c < ccnt)
          acc[b][c] += qv.x*kv[c].x + qv.y*kv[c].y + qv.z*kv[c].z + qv.w*kv[c].w;
      if (w == 3)
        qq[b] += qv.x*qv.x + qv.y*qv.y + qv.z*qv.z + qv.w*qv.w;
    }
  }

  const size_t pb = (size_t)(lc * NBT + bt) * 16;
#pragma unroll
  for (int b = 0; b < BTILE; ++b) {
#pragma unroll
    for (int c = 0; c < 4; ++c) {
      float v = wave_sum(acc[b][c]);
      if (lane == 0 && c < ccnt) part[(pb + cbase + c) * 8 + b] = v;
    }
    if (w == 3) {
      float v = wave_sum(qq[b]);
      if (lane == 0) part[(pb + 15) * 8 + b] = v;
    }
  }
  if (bt == 0) {
#pragma unroll
    for (int c = 0; c < 4; ++c) {
      float v = wave_sum(kkv[c]);
      if (lane == 0 && c < ccnt) kkpart[lc * 16 + cbase + c] = v;
    }
  }
}

// Final reduce: 1 block, thread b handles query b.
__global__ __launch_bounds__(256) void retrieve_reduce(
    const float* __restrict__ part, const float* __restrict__ kkpart,
    float* __restrict__ out) {
  __shared__ float kn[NCLS];
  const int t = threadIdx.x;
  if (t < NCLS) {
    float s = 0.f;
    for (int lc = 0; lc < NCHUNK; ++lc) s += kkpart[lc * 16 + t];
    kn[t] = s;
  }
  __syncthreads();
  const int bt = t >> 3, bi = t & 7;
  float qq = 0.f;
  for (int lc = 0; lc < NCHUNK; ++lc)
    qq += part[((size_t)(lc * NBT + bt) * 16 + 15) * 8 + bi];
  float dmin = INFINITY;
  int didx = 0;
  for (int c = 0; c < NCLS; ++c) {
    float dot = 0.f;
    for (int lc = 0; lc < NCHUNK; ++lc)
      dot += part[((size_t)(lc * NBT + bt) * 16 + c) * 8 + bi];
    float d2 = qq + kn[c] - 2.f * dot;
    float d = sqrtf(fmaxf(d2, 1e-12f));
    if (d < dmin) { dmin = d; didx = c; }
  }
  out[t] = dmin;
  out[256 + t] = (float)didx;
}

// Persistent cooperative FPS kernel. 256 blocks x 1024 threads, 1 block/CU.
// Embedding slice lives in LDS (deterministic residency, no regalloc whims).
// Cross-block sync: RELAXED-only atomics. Each block posts one 64-bit word
//   word = (step << 48) | (dist_bits << 16) | point_idx
// into a step-parity double buffer; pollers spin with relaxed loads until
// tag >= step. Payload rides inside the word, so no acquire/release (and
// thus no per-iteration buffer_inv / L2 flush) is needed. Double-buffering
// guarantees a word is never overwritten while a slower block still needs
// it (a block cannot post step s+2 before every block posted s+1).
__global__ __launch_bounds__(1024, 4) void fps_kernel(
    const float* __restrict__ emb,
    u64* __restrict__ words,                  // [2*NBLK], memset 0 per launch
    float* __restrict__ out_samples) {
  extern __shared__ float e_lds[];            // [PPB*DIM] = 150528 B
  const int tid = threadIdx.x;
  const int blk = blockIdx.x;
  const int w = tid >> 6, lane = tid & 63;

  __shared__ int hist[NSAMP];
  __shared__ u64 wkey[16];
  __shared__ u64 swin[4];

  // Stage this block's 49 embedding rows into LDS (coalesced).
  {
    const float* src = emb + (size_t)blk * EPB;
    for (int i = tid; i < EPB; i += 1024) e_lds[i] = src[i];
  }
  __syncthreads();

  // Per-wave points p = w + 16*i; squared norms (same association as before).
  float sq[NPPW];
  float dist2[NPPW];
#pragma unroll
  for (int i = 0; i < NPPW; ++i) {
    const int p = w + 16 * i;
    float s = 0.f;
    if (p < PPB) {
#pragma unroll
      for (int j = 0; j < 12; ++j) {
        float v = e_lds[p * DIM + lane + 64 * j];
        s += v * v;
      }
    }
    sq[i] = wave_sum(s);
    dist2[i] = INFINITY;
  }
  int last = 0;
  if (tid == 0) hist[0] = 0;
  __syncthreads();

  for (int s = 1; s < NSAMP; ++s) {
    const int buf = (s & 1) * NBLK;

    // Load centroid row (uniform), compute |c|^2 — same arithmetic as before.
    float c[12];
    float cn = 0.f;
    const size_t cb = (size_t)last * DIM;
#pragma unroll
    for (int j = 0; j < 12; ++j) {
      float v = emb[cb + lane + 64 * j];
      c[j] = v;
      cn += v * v;
    }
    cn = wave_sum(cn);

    // Update running min (squared space); wave-local best key.
    u64 bk = 0ull;
#pragma unroll
    for (int i = 0; i < NPPW; ++i) {
      const int p = w + 16 * i;
      if (p < PPB) {
        float a = 0.f;
#pragma unroll
        for (int j = 0; j < 12; ++j) a = fmaf(e_lds[p * DIM + lane + 64 * j], c[j], a);
        a = wave_sum(a);
        float d2 = sq[i] - 2.f * a + cn;
        if (d2 < dist2[i]) dist2[i] = d2;
        u32 fb = __float_as_uint(dist2[i]);
        u64 key = ((u64)fb << 32) | (u32)(~(u32)(blk * PPB + p));
        if (key > bk) bk = key;
      }
    }
    if (lane == 0) wkey[w] = bk;
    __syncthreads();
    if (tid == 0) {
      u64 m = wkey[0];
#pragma unroll
      for (int qi = 1; qi < 16; ++qi) if (wkey[qi] > m) m = wkey[qi];
      const u32 bidx = ~(u32)(m & 0xffffffffull);   // global point idx (<12544)
      const u32 bdist = (u32)(m >> 32);
      const u64 word = ((u64)s << 48) | ((u64)bdist << 16) | (u64)bidx;
      __hip_atomic_store(&words[buf + blk], word, __ATOMIC_RELAXED,
                         __HIP_MEMORY_SCOPE_AGENT);
    }

    // Poll all 256 slots (relaxed, payload-in-word), reduce to global winner.
    if (tid < NBLK) {
      u64 w64;
      for (;;) {
        w64 = __hip_atomic_load(&words[buf + tid], __ATOMIC_RELAXED,
                                __HIP_MEMORY_SCOPE_AGENT);
        if ((w64 >> 48) >= (u64)s) break;
        __builtin_amdgcn_s_sleep(1);
      }
      // Reconstruct the cross-block comparison key (identical bit pattern
      // to the per-point keys: (dist_bits << 32) | ~idx).
      const u64 kk = (((w64 >> 16) & 0xffffffffull) << 32) |
                     (u64)(u32)(~(u32)(w64 & 0xffffull));
      const u64 km = wave_max_u64(kk);
      if (lane == 0) swin[w] = km;
    }
    __syncthreads();
    if (tid == 0) {
      u64 m = swin[0];
#pragma unroll
      for (int qi = 1; qi < 4; ++qi) if (swin[qi] > m) m = swin[qi];
      hist[s] = (int)(~(u32)(m & 0xffffffffull));
    }
    __syncthreads();
    last = hist[s];
  }

  // Gather samples: block blk copies row hist[blk] (no cross-block dep).
  if (blk < NSAMP) {
    const int idx = hist[blk];
    const float4* src = (const float4*)(emb + (size_t)idx * DIM);
    float4* dst = (float4*)(out_samples + (size_t)blk * DIM);
    if (tid < DIM / 4) dst[tid] = src[tid];
  }
}

extern "C" void kernel_launch(void* const* d_in, const int* in_sizes, int n_in,
                              void* d_out, int out_size, void* d_ws, size_t ws_size,
                              hipStream_t stream) {
  const float* q   = (const float*)d_in[0];   // [256, 196, 768]
  const float* k   = (const float*)d_in[1];   // [15, 196, 768]
  const float* emb = (const float*)d_in[2];   // [12544, 768]
  float* out = (float*)d_out;                 // [256 dist | 256 idx | 196*768 samples]

  u64* words = (u64*)d_ws;                                      // 512 u64 = 4096 B
  float* part   = (float*)((char*)d_ws + 4096);                 // 7*32*16*8 = 28672 f
  float* kkpart = part + 28672;                                 // 112 f

  // Reset sync words (stale tags from prior replays must not alias).
  hipMemsetAsync(words, 0, 2 * NBLK * sizeof(u64), stream);

  hipLaunchKernelGGL(retrieve_partial, dim3(NBT, NCHUNK), dim3(256), 0, stream,
                     q, k, part, kkpart);
  hipLaunchKernelGGL(retrieve_reduce, dim3(1), dim3(256), 0, stream,
                     part, kkpart, out);

  static int smem_attr_set = 0;
  (void)smem_attr_set;  // host-side, idempotent, not a stream op
  hipFuncSetAttribute((const void*)fps_kernel,
                      hipFuncAttributeMaxDynamicSharedMemorySize,
                      EPB * sizeof(float));

  float* samples = out + 512;
  void* args[] = {(void*)&emb, (void*)&words, (void*)&samples};
  hipLaunchCooperativeKernel((void*)fps_kernel, dim3(NBLK), dim3(1024), args,
                             EPB * sizeof(float), stream);
}

// Round 4
// 879.329 us; speedup vs baseline: 11.6409x; 1.2993x over previous
//
#include <hip/hip_runtime.h>
#include <math.h>

typedef unsigned long long u64;
typedef unsigned int u32;

// ---------------- retrieve_key: [256] queries vs [15] keys over L=150528 ----
#define L_TOT  150528
#define ROW4   37632      // L_TOT/4 float4 per row
#define NCHUNK 7
#define CH4    5376       // ROW4/NCHUNK
#define R_ITERS 84        // CH4/64
#define NBT    32         // b-tiles of 8
#define BTILE  8
#define NCLS   15

// ---------------- FPS ------------------------------------------------------
#define N_E    12544
#define DIM    768
#define NBLK   256
#define PPB    49         // points per block (256*49 = 12544, exact)
#define NPPW   4          // max points per wave (wave 0 gets 4, others 3)
#define NSAMP  196
#define EPB    (PPB*DIM)  // 37632 floats = 150528 B in LDS

__device__ __forceinline__ float wave_sum(float v) {
#pragma unroll
  for (int m = 1; m < 64; m <<= 1) v += __shfl_xor(v, m, 64);
  return v;
}

__device__ __forceinline__ u64 wave_max_u64(u64 v) {
#pragma unroll
  for (int m = 1; m < 64; m <<= 1) {
    u64 o = __shfl_xor(v, m, 64);
    if (o > v) v = o;
  }
  return v;
}

// Partial dot products: grid (32 b-tiles, 7 L-chunks), block 256.
__global__ __launch_bounds__(256) void retrieve_partial(
    const float* __restrict__ q, const float* __restrict__ k,
    float* __restrict__ part, float* __restrict__ kkpart) {
  const int bt = blockIdx.x;     // 0..31
  const int lc = blockIdx.y;     // 0..6
  const int tid = threadIdx.x;
  const int w = tid >> 6, lane = tid & 63;
  const int cbase = w * 4;
  const int ccnt = (w == 3) ? 3 : 4;
  const float4* qf = (const float4*)q;
  const float4* kf = (const float4*)k;
  const int fbase = lc * CH4 + lane;

  float acc[BTILE][4];
  float qq[BTILE];
  float kkv[4];
#pragma unroll
  for (int b = 0; b < BTILE; ++b) {
    qq[b] = 0.f;
#pragma unroll
    for (int c = 0; c < 4; ++c) acc[b][c] = 0.f;
  }
#pragma unroll
  for (int c = 0; c < 4; ++c) kkv[c] = 0.f;

  for (int it = 0; it < R_ITERS; ++it) {
    const int f = fbase + it * 64;
    float4 kv[4];
#pragma unroll
    for (int c = 0; c < 4; ++c)
      if (c < ccnt) kv[c] = kf[(size_t)(cbase + c) * ROW4 + f];
    if (bt == 0) {
#pragma unroll
      for (int c = 0; c < 4; ++c)
        if (c < ccnt)
          kkv[c] += kv[c].x*kv[c].x + kv[c].y*kv[c].y + kv[c].z*kv[c].z + kv[c].w*kv[c].w;
    }
#pragma unroll
    for (int b = 0; b < BTILE; ++b) {
      float4 qv = qf[(size_t)(bt * BTILE + b) * ROW4 + f];
#pragma unroll
      for (int c = 0; c < 4; ++c)
        if (c < ccnt)
          acc[b][c] += qv.x*kv[c].x + qv.y*kv[c].y + qv.z*kv[c].z + qv.w*kv[c].w;
      if (w == 3)
        qq[b] += qv.x*qv.x + qv.y*qv.y + qv.z*qv.z + qv.w*qv.w;
    }
  }

  const size_t pb = (size_t)(lc * NBT + bt) * 16;
#pragma unroll
  for (int b = 0; b < BTILE; ++b) {
#pragma unroll
    for (int c = 0; c < 4; ++c) {
      float v = wave_sum(acc[b][c]);
      if (lane == 0 && c < ccnt) part[(pb + cbase + c) * 8 + b] = v;
    }
    if (w == 3) {
      float v = wave_sum(qq[b]);
      if (lane == 0) part[(pb + 15) * 8 + b] = v;
    }
  }
  if (bt == 0) {
#pragma unroll
    for (int c = 0; c < 4; ++c) {
      float v = wave_sum(kkv[c]);
      if (lane == 0 && c < ccnt) kkpart[lc * 16 + cbase + c] = v;
    }
  }
}

// Final reduce: 1 block, thread b handles query b.
__global__ __launch_bounds__(256) void retrieve_reduce(
    const float* __restrict__ part, const float* __restrict__ kkpart,
    float* __restrict__ out) {
  __shared__ float kn[NCLS];
  const int t = threadIdx.x;
  if (t < NCLS) {
    float s = 0.f;
    for (int lc = 0; lc < NCHUNK; ++lc) s += kkpart[lc * 16 + t];
    kn[t] = s;
  }
  __syncthreads();
  const int bt = t >> 3, bi = t & 7;
  float qq = 0.f;
  for (int lc = 0; lc < NCHUNK; ++lc)
    qq += part[((size_t)(lc * NBT + bt) * 16 + 15) * 8 + bi];
  float dmin = INFINITY;
  int didx = 0;
  for (int c = 0; c < NCLS; ++c) {
    float dot = 0.f;
    for (int lc = 0; lc < NCHUNK; ++lc)
      dot += part[((size_t)(lc * NBT + bt) * 16 + c) * 8 + bi];
    float d2 = qq + kn[c] - 2.f * dot;
    float d = sqrtf(fmaxf(d2, 1e-12f));
    if (d < dmin) { dmin = d; didx = c; }
  }
  out[t] = dmin;
  out[256 + t] = (float)didx;
}

// Persistent cooperative FPS kernel. 256 blocks x 1024 threads, 1 block/CU.
// Embedding slice resident in LDS. Cross-block sync is hierarchical and
// relaxed-only (payload rides inside each atomic word; no acquire/release,
// no cache-invalidate storms):
//   phase 1: block b posts (step<<48)|(dist<<16)|idx to words[parity][b]
//   phase 2: block 0 alone polls the 256 words, reduces, posts
//            result[parity] = (step<<32)|winner_idx
//   phase 3: each block polls result with ONE thread, broadcasts via LDS.
// Overwrite safety: a block posts step s+1 only after observing result[s],
// which the hub posts only after reading every phase-1 word of step s; the
// parity double buffer therefore never gets overwritten while still needed.
// Max-reductions are exact u64 compares -> any reduce order gives identical
// winners; all FP arithmetic is bit-identical to the previous rounds.
__global__ __launch_bounds__(1024, 4) void fps_kernel(
    const float* __restrict__ emb,
    u64* __restrict__ words,                  // [2*NBLK], memset 0 per launch
    u64* __restrict__ result,                 // [2], memset 0 per launch
    float* __restrict__ out_samples) {
  extern __shared__ float e_lds[];            // [PPB*DIM] = 150528 B
  const int tid = threadIdx.x;
  const int blk = blockIdx.x;
  const int w = tid >> 6, lane = tid & 63;

  __shared__ int hist[NSAMP];
  __shared__ u64 wkey[16];
  __shared__ u64 swin[4];

  // Stage this block's 49 embedding rows into LDS (coalesced).
  {
    const float* src = emb + (size_t)blk * EPB;
    for (int i = tid; i < EPB; i += 1024) e_lds[i] = src[i];
  }
  __syncthreads();

  // Per-wave points p = w + 16*i; squared norms (same association as before).
  float sq[NPPW];
  float dist2[NPPW];
#pragma unroll
  for (int i = 0; i < NPPW; ++i) {
    const int p = w + 16 * i;
    float s = 0.f;
    if (p < PPB) {
#pragma unroll
      for (int j = 0; j < 12; ++j) {
        float v = e_lds[p * DIM + lane + 64 * j];
        s += v * v;
      }
    }
    sq[i] = wave_sum(s);
    dist2[i] = INFINITY;
  }
  int last = 0;
  if (tid == 0) hist[0] = 0;
  __syncthreads();

  for (int s = 1; s < NSAMP; ++s) {
    const int buf = (s & 1) * NBLK;

    // Load centroid row (uniform), compute |c|^2 — same arithmetic as before.
    float c[12];
    float cn = 0.f;
    const size_t cb = (size_t)last * DIM;
#pragma unroll
    for (int j = 0; j < 12; ++j) {
      float v = emb[cb + lane + 64 * j];
      c[j] = v;
      cn += v * v;
    }
    cn = wave_sum(cn);

    // Update running min (squared space); wave-local best key.
    u64 bk = 0ull;
#pragma unroll
    for (int i = 0; i < NPPW; ++i) {
      const int p = w + 16 * i;
      if (p < PPB) {
        float a = 0.f;
#pragma unroll
        for (int j = 0; j < 12; ++j) a = fmaf(e_lds[p * DIM + lane + 64 * j], c[j], a);
        a = wave_sum(a);
        float d2 = sq[i] - 2.f * a + cn;
        if (d2 < dist2[i]) dist2[i] = d2;
        u32 fb = __float_as_uint(dist2[i]);
        u64 key = ((u64)fb << 32) | (u32)(~(u32)(blk * PPB + p));
        if (key > bk) bk = key;
      }
    }
    if (lane == 0) wkey[w] = bk;
    __syncthreads();

    // Phase 1: wave-0 16-lane butterfly block-reduce (exact max, order-free),
    // lane 0 posts the step-tagged word.
    if (w == 0) {
      u64 k = wkey[lane & 15];
#pragma unroll
      for (int m = 1; m < 16; m <<= 1) {
        u64 o = __shfl_xor(k, m, 64);
        if (o > k) k = o;
      }
      if (lane == 0) {
        const u32 bidx = ~(u32)(k & 0xffffffffull);   // global point idx
        const u32 bdist = (u32)(k >> 32);
        const u64 word = ((u64)s << 48) | ((u64)bdist << 16) | (u64)bidx;
        __hip_atomic_store(&words[buf + blk], word, __ATOMIC_RELAXED,
                           __HIP_MEMORY_SCOPE_AGENT);
      }
    }

    if (blk == 0) {
      // Phase 2 (hub): poll all 256 words, reduce, publish result.
      if (tid < NBLK) {
        u64 w64;
        for (;;) {
          w64 = __hip_atomic_load(&words[buf + tid], __ATOMIC_RELAXED,
                                  __HIP_MEMORY_SCOPE_AGENT);
          if ((w64 >> 48) >= (u64)s) break;
        }
        u64 kk = (((w64 >> 16) & 0xffffffffull) << 32) |
                 (u64)(u32)(~(u32)(w64 & 0xffffull));
        kk = wave_max_u64(kk);
        if (lane == 0) swin[w] = kk;
      }
      __syncthreads();
      if (tid == 0) {
        u64 m = swin[0];
#pragma unroll
        for (int qi = 1; qi < 4; ++qi) if (swin[qi] > m) m = swin[qi];
        const int widx = (int)(~(u32)(m & 0xffffffffull));
        hist[s] = widx;
        __hip_atomic_store(&result[s & 1], ((u64)s << 32) | (u32)widx,
                           __ATOMIC_RELAXED, __HIP_MEMORY_SCOPE_AGENT);
      }
      __syncthreads();
    } else {
      // Phase 3: one thread polls the single result word.
      if (tid == 0) {
        u64 r;
        for (;;) {
          r = __hip_atomic_load(&result[s & 1], __ATOMIC_RELAXED,
                                __HIP_MEMORY_SCOPE_AGENT);
          if ((r >> 32) >= (u64)s) break;
        }
        hist[s] = (int)(u32)(r & 0xffffffffull);
      }
      __syncthreads();
    }
    last = hist[s];
  }

  // Gather samples: block blk copies row hist[blk] (no cross-block dep).
  if (blk < NSAMP) {
    const int idx = hist[blk];
    const float4* src = (const float4*)(emb + (size_t)idx * DIM);
    float4* dst = (float4*)(out_samples + (size_t)blk * DIM);
    if (tid < DIM / 4) dst[tid] = src[tid];
  }
}

extern "C" void kernel_launch(void* const* d_in, const int* in_sizes, int n_in,
                              void* d_out, int out_size, void* d_ws, size_t ws_size,
                              hipStream_t stream) {
  const float* q   = (const float*)d_in[0];   // [256, 196, 768]
  const float* k   = (const float*)d_in[1];   // [15, 196, 768]
  const float* emb = (const float*)d_in[2];   // [12544, 768]
  float* out = (float*)d_out;                 // [256 dist | 256 idx | 196*768 samples]

  u64* words  = (u64*)d_ws;                                     // [512] = 4096 B
  u64* result = (u64*)((char*)d_ws + 4096);                     // [2]   = 16 B
  float* part   = (float*)((char*)d_ws + 8192);                 // 7*32*16*8 = 28672 f
  float* kkpart = part + 28672;                                 // 112 f

  // Reset sync words (stale tags from prior replays must not alias).
  hipMemsetAsync(d_ws, 0, 4096 + 16, stream);

  hipLaunchKernelGGL(retrieve_partial, dim3(NBT, NCHUNK), dim3(256), 0, stream,
                     q, k, part, kkpart);
  hipLaunchKernelGGL(retrieve_reduce, dim3(1), dim3(256), 0, stream,
                     part, kkpart, out);

  hipFuncSetAttribute((const void*)fps_kernel,
                      hipFuncAttributeMaxDynamicSharedMemorySize,
                      EPB * sizeof(float));

  float* samples = out + 512;
  void* args[] = {(void*)&emb, (void*)&words, (void*)&result, (void*)&samples};
  hipLaunchCooperativeKernel((void*)fps_kernel, dim3(NBLK), dim3(1024), args,
                             EPB * sizeof(float), stream);
}